// Round 8
// baseline (235.897 us; speedup 1.0000x reference)
//
#include <hip/hip_runtime.h>

#define N_NODES 100000
#define N_EDGES 1600000
#define D 128
#define N_STRIPS (N_NODES / 32)     // 3125

#define BSH   8                     // bucket = col >> 8 (256 nodes/bucket)
#define NBKT  391                   // ceil(100000 / 256)
#define ARENA 5120                  // per-bucket arena slots (mean 4096 + 16 sigma)
#define SC_BLK 256                  // scatter blocks; 6250 edges each, exact
#define EPS   (N_EDGES / SC_BLK)

typedef __bf16 bf16x8 __attribute__((ext_vector_type(8)));
typedef float  f32x4  __attribute__((ext_vector_type(4)));

// ---- K1: hb[row] = bf16((x @ W^T)[row]) via MFMA, W cast on the fly;
// block 0 also zeroes the arena counters ----
__global__ __launch_bounds__(256) void k_hx(const float* __restrict__ x,
                                            const float* __restrict__ w,
                                            __bf16* __restrict__ hb,
                                            int* __restrict__ gcnt) {
    if (blockIdx.x == 0) {
        for (int i = threadIdx.x; i < NBKT; i += 256) gcnt[i] = 0;
    }
    int wave = threadIdx.x >> 6;
    int lane = threadIdx.x & 63;
    int strip = blockIdx.x * 4 + wave;
    if (strip >= N_STRIPS) return;
    int m0 = strip * 32;
    int l15 = lane & 15;
    int kq  = lane >> 4;

    bf16x8 a[2][4];
    #pragma unroll
    for (int mt = 0; mt < 2; ++mt) {
        const float* ap = x + (size_t)(m0 + mt * 16 + l15) * D + kq * 8;
        #pragma unroll
        for (int ks = 0; ks < 4; ++ks) {
            float4 lo = *(const float4*)(ap + ks * 32);
            float4 hi = *(const float4*)(ap + ks * 32 + 4);
            bf16x8 t;
            t[0] = (__bf16)lo.x; t[1] = (__bf16)lo.y;
            t[2] = (__bf16)lo.z; t[3] = (__bf16)lo.w;
            t[4] = (__bf16)hi.x; t[5] = (__bf16)hi.y;
            t[6] = (__bf16)hi.z; t[7] = (__bf16)hi.w;
            a[mt][ks] = t;
        }
    }

    f32x4 acc[2][8] = {};
    #pragma unroll
    for (int ks = 0; ks < 4; ++ks) {
        #pragma unroll
        for (int nt = 0; nt < 8; ++nt) {
            const float* bp = w + (size_t)(nt * 16 + l15) * D + ks * 32 + kq * 8;
            float4 lo = *(const float4*)bp;
            float4 hi = *(const float4*)(bp + 4);
            bf16x8 bfr;
            bfr[0] = (__bf16)lo.x; bfr[1] = (__bf16)lo.y;
            bfr[2] = (__bf16)lo.z; bfr[3] = (__bf16)lo.w;
            bfr[4] = (__bf16)hi.x; bfr[5] = (__bf16)hi.y;
            bfr[6] = (__bf16)hi.z; bfr[7] = (__bf16)hi.w;
            acc[0][nt] = __builtin_amdgcn_mfma_f32_16x16x32_bf16(a[0][ks], bfr, acc[0][nt], 0, 0, 0);
            acc[1][nt] = __builtin_amdgcn_mfma_f32_16x16x32_bf16(a[1][ks], bfr, acc[1][nt], 0, 0, 0);
        }
    }

    #pragma unroll
    for (int nt = 0; nt < 8; ++nt) {
        int colj = nt * 16 + l15;
        #pragma unroll
        for (int mt = 0; mt < 2; ++mt) {
            #pragma unroll
            for (int r = 0; r < 4; ++r) {
                int rowi = m0 + mt * 16 + kq * 4 + r;
                hb[(size_t)rowi * D + colj] = (__bf16)acc[mt][nt][r];
            }
        }
    }
}

// ---- K2: self-reserving scatter into per-bucket arenas.
// Per block: LDS-count slice, one global atomicAdd per bucket to reserve a
// window, then scatter records (row<<8 | col&255) from the LDS-cached slice ----
__global__ __launch_bounds__(1024) void k_scatter(const int* __restrict__ row,
                                                  const int* __restrict__ col,
                                                  int* __restrict__ gcnt,
                                                  unsigned* __restrict__ arena) {
    __shared__ int rc[EPS];
    __shared__ int cc[EPS];
    __shared__ int lcnt[NBKT];
    __shared__ int lbase[NBKT];
    int b = blockIdx.x, t = threadIdx.x;
    if (t < NBKT) lcnt[t] = 0;
    __syncthreads();
    int e0 = b * EPS;
    for (int i = t; i < EPS; i += 1024) {
        int r = row[e0 + i], c = col[e0 + i];
        rc[i] = r; cc[i] = c;
        atomicAdd(&lcnt[c >> BSH], 1);
    }
    __syncthreads();
    if (t < NBKT) lbase[t] = atomicAdd(&gcnt[t], lcnt[t]);
    __syncthreads();
    if (t < NBKT) lcnt[t] = 0;               // reuse as cursor
    __syncthreads();
    for (int i = t; i < EPS; i += 1024) {
        int c = cc[i];
        int k = c >> BSH;
        int idx = lbase[k] + atomicAdd(&lcnt[k], 1);
        if (idx < ARENA)
            arena[(size_t)k * ARENA + idx] = ((unsigned)rc[i] << BSH) | (unsigned)(c & ((1 << BSH) - 1));
    }
}

// ---- K3: per-bucket fine counting sort from arena (bucket cached in LDS);
// emits deg/dis/start and rewrites the arena in place as srcs byte offsets ----
__global__ __launch_bounds__(1024) void k_fine(unsigned* __restrict__ arena,
                                               const int* __restrict__ gcnt,
                                               int* __restrict__ deg,
                                               float* __restrict__ dis,
                                               int* __restrict__ start) {
    __shared__ unsigned cache[ARENA];
    __shared__ int fh[256];
    __shared__ int fsc[256];
    int b = blockIdx.x;
    int tid = threadIdx.x;
    int cnt = gcnt[b]; if (cnt > ARENA) cnt = ARENA;
    int gs = b * ARENA;
    if (tid < 256) fh[tid] = 0;
    __syncthreads();
    for (int i = tid; i < cnt; i += 1024) {
        unsigned r = arena[gs + i];
        cache[i] = r;
        atomicAdd(&fh[r & 255], 1);
    }
    __syncthreads();
    int v = 0;
    if (tid < 256) { v = fh[tid]; fsc[tid] = v; }
    __syncthreads();
    for (int off = 1; off < 256; off <<= 1) {
        int u = 0;
        if (tid < 256 && tid >= off) u = fsc[tid - off];
        __syncthreads();
        if (tid < 256) fsc[tid] += u;
        __syncthreads();
    }
    if (tid < 256) {
        int excl = fsc[tid] - v;              // exclusive scan value
        int node = (b << BSH) + tid;
        if (node < N_NODES) {
            deg[node]   = v;
            dis[node]   = rsqrtf((float)v + 1.0f);
            start[node] = gs + excl;
        }
        fh[tid] = excl;                       // -> cursors
    }
    __syncthreads();
    for (int i = tid; i < cnt; i += 1024) {
        unsigned r = cache[i];
        int pos = atomicAdd(&fh[r & 255], 1);
        arena[gs + pos] = (r >> BSH) << 8;    // row * 256 = byte offset into hb
    }
}

// ---- K4: gather-aggregate, one wave per destination, 32 lanes x 8B per row,
// two source rows per VMEM instruction; per-edge norm dis[src] gathered and
// shuffled alongside; out = dc*(sum + dc*h[node]) + bias, relu ----
__global__ __launch_bounds__(256) void k_aggregate(const unsigned* __restrict__ srcs,
                                                   const int* __restrict__ start,
                                                   const int* __restrict__ deg,
                                                   const __bf16* __restrict__ hb,
                                                   const float* __restrict__ dis,
                                                   const float* __restrict__ bias,
                                                   float* __restrict__ out) {
    int node = (blockIdx.x * 256 + threadIdx.x) >> 6;
    int lane = threadIdx.x & 63;
    if (node >= N_NODES) return;
    int li   = lane & 31;          // 8B slot within row (cols 4*li .. 4*li+3)
    int half = lane >> 5;          // which of 2 edges this half-wave handles
    int s = start[node];
    int n = deg[node];
    float dc = dis[node];
    const unsigned char* hbase = (const unsigned char*)hb;
    size_t boff = (size_t)li * 8;

    float acc0 = 0.f, acc1 = 0.f, acc2 = 0.f, acc3 = 0.f;

    for (int base = 0; base < n; base += 64) {
        int m = n - base; if (m > 64) m = 64;
        int   src_l = 0;
        float nr_l  = 0.f;
        if (lane < m) {
            src_l = (int)srcs[s + base + lane];          // byte offset row<<8
            nr_l  = dis[src_l >> 8];
        }
        int i = 0;
        for (; i + 16 <= m; i += 16) {          // 16 edges per batch (8 per half)
            int sv[8]; float nv[8]; uint2 av[8];
            #pragma unroll
            for (int j = 0; j < 8; ++j) {
                sv[j] = __shfl(src_l, i + 2 * j + half);
                nv[j] = __shfl(nr_l, i + 2 * j + half);
            }
            #pragma unroll
            for (int j = 0; j < 8; ++j)
                av[j] = *(const uint2*)(hbase + ((size_t)sv[j] + boff));
            #pragma unroll
            for (int j = 0; j < 8; ++j) {
                acc0 += __uint_as_float(av[j].x << 16) * nv[j];
                acc1 += __uint_as_float(av[j].x & 0xFFFF0000u) * nv[j];
                acc2 += __uint_as_float(av[j].y << 16) * nv[j];
                acc3 += __uint_as_float(av[j].y & 0xFFFF0000u) * nv[j];
            }
        }
        for (; i + 2 <= m; i += 2) {            // 2 edges per step
            int   sj = __shfl(src_l, i + half);
            float nj = __shfl(nr_l, i + half);
            uint2 a = *(const uint2*)(hbase + ((size_t)sj + boff));
            acc0 += __uint_as_float(a.x << 16) * nj;
            acc1 += __uint_as_float(a.x & 0xFFFF0000u) * nj;
            acc2 += __uint_as_float(a.y << 16) * nj;
            acc3 += __uint_as_float(a.y & 0xFFFF0000u) * nj;
        }
        if (i < m) {                            // odd leftover: half 0 only
            int   sj = __shfl(src_l, i);
            float nj = __shfl(nr_l, i);
            if (half == 0) {
                uint2 a = *(const uint2*)(hbase + ((size_t)sj + boff));
                acc0 += __uint_as_float(a.x << 16) * nj;
                acc1 += __uint_as_float(a.x & 0xFFFF0000u) * nj;
                acc2 += __uint_as_float(a.y << 16) * nj;
                acc3 += __uint_as_float(a.y & 0xFFFF0000u) * nj;
            }
        }
    }

    // combine the two halves
    acc0 += __shfl_xor(acc0, 32);
    acc1 += __shfl_xor(acc1, 32);
    acc2 += __shfl_xor(acc2, 32);
    acc3 += __shfl_xor(acc3, 32);

    if (half == 0) {
        // self-loop term: + dc * h[node] inside the dc-scaled sum
        uint2 a = *(const uint2*)(hbase + ((size_t)node * 256 + boff));
        acc0 += __uint_as_float(a.x << 16) * dc;
        acc1 += __uint_as_float(a.x & 0xFFFF0000u) * dc;
        acc2 += __uint_as_float(a.y << 16) * dc;
        acc3 += __uint_as_float(a.y & 0xFFFF0000u) * dc;

        float4 b4 = *(const float4*)(bias + li * 4);
        float4 r;
        r.x = fmaxf(acc0 * dc + b4.x, 0.f);
        r.y = fmaxf(acc1 * dc + b4.y, 0.f);
        r.z = fmaxf(acc2 * dc + b4.z, 0.f);
        r.w = fmaxf(acc3 * dc + b4.w, 0.f);
        *(float4*)(out + (size_t)node * D + li * 4) = r;
    }
}

extern "C" void kernel_launch(void* const* d_in, const int* in_sizes, int n_in,
                              void* d_out, int out_size, void* d_ws, size_t ws_size,
                              hipStream_t stream) {
    const float* x    = (const float*)d_in[0];
    const int*   ei   = (const int*)d_in[1];    // [2, E]: row then col
    const float* w    = (const float*)d_in[2];
    const float* bias = (const float*)d_in[3];
    float* out = (float*)d_out;

    char* ws = (char*)d_ws;
    int*      deg    = (int*)ws;              ws += N_NODES * 4;
    float*    dis    = (float*)ws;            ws += N_NODES * 4;
    int*      start  = (int*)ws;              ws += N_NODES * 4;
    int*      gcnt   = (int*)ws;              ws += 512 * 4;
    unsigned* arena  = (unsigned*)ws;         ws += (size_t)NBKT * ARENA * 4;  // grec -> srcs in place
    __bf16*   hb     = (__bf16*)ws;           // N_NODES * D * 2 = 25.6 MB

    const int* row = ei;
    const int* col = ei + N_EDGES;

    k_hx       <<<(N_STRIPS + 3) / 4, 256, 0, stream>>>(x, w, hb, gcnt);
    k_scatter  <<<SC_BLK, 1024, 0, stream>>>(row, col, gcnt, arena);
    k_fine     <<<NBKT, 1024, 0, stream>>>(arena, gcnt, deg, dis, start);
    k_aggregate<<<(N_NODES * 64 + 255) / 256, 256, 0, stream>>>(arena, start, deg, hb, dis, bias, out);
}

// Round 9
// 224.727 us; speedup vs baseline: 1.0497x; 1.0497x over previous
//
#include <hip/hip_runtime.h>

#define N_NODES 100000
#define N_EDGES 1600000
#define D 128
#define N_STRIPS (N_NODES / 32)     // 3125

#define BSH   9                     // coarse bucket = col >> 9 (512 nodes/bucket)
#define NBKT  196                   // ceil(100000 / 512)
#define P_BLK 512                   // partition blocks; EPB = 3125 exactly
#define EPB   (N_EDGES / P_BLK)

typedef __bf16 bf16x4 __attribute__((ext_vector_type(4)));
typedef __bf16 bf16x8 __attribute__((ext_vector_type(8)));
typedef float  f32x4  __attribute__((ext_vector_type(4)));

// ---- P1 fused: blocks 0..P_BLK-1 build coarse histogram; block P_BLK casts W ----
__global__ __launch_bounds__(1024) void k_prep(const int* __restrict__ col,
                                               const float4* __restrict__ w4,
                                               int* __restrict__ bhist,
                                               bf16x4* __restrict__ wb4) {
    int tid = threadIdx.x, b = blockIdx.x;
    if (b == P_BLK) {                      // cast W -> bf16 (4096 float4)
        for (int i = tid; i < (D * D) / 4; i += 1024) {
            float4 u = w4[i];
            bf16x4 p;
            p[0] = (__bf16)u.x; p[1] = (__bf16)u.y;
            p[2] = (__bf16)u.z; p[3] = (__bf16)u.w;
            wb4[i] = p;
        }
        return;
    }
    __shared__ int lh[NBKT];
    if (tid < NBKT) lh[tid] = 0;
    __syncthreads();
    int e0 = b * EPB;
    for (int e = e0 + tid; e < e0 + EPB; e += 1024)
        atomicAdd(&lh[col[e] >> BSH], 1);
    __syncthreads();
    if (tid < NBKT) bhist[tid * P_BLK + b] = lh[tid];
}

// ---- P2a: per-bucket exclusive scan over the 512 block counts (in place) ----
__global__ __launch_bounds__(512) void k_bscan(int* __restrict__ bhist,
                                               int* __restrict__ gtot) {
    __shared__ int buf[512];
    int k = blockIdx.x, t = threadIdx.x;
    int v = bhist[k * P_BLK + t];
    buf[t] = v;
    __syncthreads();
    for (int off = 1; off < 512; off <<= 1) {
        int u = (t >= off) ? buf[t - off] : 0;
        __syncthreads();
        buf[t] += u;
        __syncthreads();
    }
    bhist[k * P_BLK + t] = buf[t] - v;   // exclusive
    if (t == 511) gtot[k] = buf[511];
}

// ---- P2b: exclusive scan of bucket totals -> gstart ----
__global__ __launch_bounds__(256) void k_gscan(const int* __restrict__ gtot,
                                               int* __restrict__ gstart) {
    __shared__ int buf[256];
    int t = threadIdx.x;
    int v = (t < NBKT) ? gtot[t] : 0;
    buf[t] = v;
    __syncthreads();
    for (int off = 1; off < 256; off <<= 1) {
        int u = (t >= off) ? buf[t - off] : 0;
        __syncthreads();
        buf[t] += u;
        __syncthreads();
    }
    if (t < NBKT) gstart[t] = buf[t] - v;
}

// ---- P3: block-local counting sort in LDS, then COALESCED window writes:
// grec[i + doff[i]] = srt[i]; consecutive lanes write consecutive addresses
// within each bucket run (avg 16 recs = 64B) ----
__global__ __launch_bounds__(1024) void k_cscatter(const int* __restrict__ row,
                                                   const int* __restrict__ col,
                                                   const int* __restrict__ bhist,
                                                   const int* __restrict__ gstart,
                                                   unsigned* __restrict__ grec) {
    __shared__ int      rec[EPB];          // packed (row<<9 | col&511)
    __shared__ unsigned short kb[EPB];     // bucket id per edge
    __shared__ int      srt[EPB];          // bucket-sorted records
    __shared__ int      dofp[EPB];         // per-record global offset delta
    __shared__ int      lh[256];           // local hist -> scan
    __shared__ int      sc[256];           // exclusive scan
    __shared__ int      cur[256];          // placement cursors
    __shared__ int      dofk[256];         // per-bucket dst delta
    int b = blockIdx.x, t = threadIdx.x;
    if (t < 256) lh[t] = 0;
    __syncthreads();
    int e0 = b * EPB;
    for (int i = t; i < EPB; i += 1024) {
        int r = row[e0 + i], c = col[e0 + i];
        int k = c >> BSH;
        rec[i] = (r << BSH) | (c & ((1 << BSH) - 1));
        kb[i]  = (unsigned short)k;
        atomicAdd(&lh[k], 1);
    }
    __syncthreads();
    int v = 0;
    if (t < 256) { v = lh[t]; sc[t] = v; }
    __syncthreads();
    for (int off = 1; off < 256; off <<= 1) {
        int u = 0;
        if (t < 256 && t >= off) u = sc[t - off];
        __syncthreads();
        if (t < 256) sc[t] += u;
        __syncthreads();
    }
    if (t < 256) {
        int excl = sc[t] - v;              // local exclusive base
        sc[t]  = excl;
        cur[t] = 0;
        dofk[t] = (t < NBKT) ? (gstart[t] + bhist[t * P_BLK + b] - excl) : 0;
    }
    __syncthreads();
    for (int i = t; i < EPB; i += 1024) {
        int k = kb[i];
        int p = sc[k] + atomicAdd(&cur[k], 1);
        srt[p]  = rec[i];
        dofp[p] = dofk[k];
    }
    __syncthreads();
    for (int i = t; i < EPB; i += 1024)
        grec[i + dofp[i]] = (unsigned)srt[i];
}

// ---- P4: per-bucket fine sort (512 nodes/bucket); emits deg/dis/start and
// srcs as pre-shifted byte offsets into hb ----
__global__ __launch_bounds__(1024) void k_fine(const unsigned* __restrict__ grec,
                                               const int* __restrict__ gtot,
                                               const int* __restrict__ gstart,
                                               int* __restrict__ deg,
                                               float* __restrict__ dis,
                                               int* __restrict__ start,
                                               int* __restrict__ srcs) {
    __shared__ int fh[512];
    __shared__ int fsc[512];
    int b = blockIdx.x;
    int tid = threadIdx.x;
    int cnt = gtot[b];
    int gs = gstart[b];
    if (tid < 512) fh[tid] = 0;
    __syncthreads();
    for (int i = tid; i < cnt; i += 1024)
        atomicAdd(&fh[grec[gs + i] & 511], 1);
    __syncthreads();
    int v = 0;
    if (tid < 512) { v = fh[tid]; fsc[tid] = v; }
    __syncthreads();
    for (int off = 1; off < 512; off <<= 1) {
        int u = 0;
        if (tid < 512 && tid >= off) u = fsc[tid - off];
        __syncthreads();
        if (tid < 512) fsc[tid] += u;
        __syncthreads();
    }
    if (tid < 512) {
        int excl = fsc[tid] - v;              // exclusive scan value
        int node = (b << BSH) + tid;
        if (node < N_NODES) {
            deg[node]   = v;
            dis[node]   = rsqrtf((float)v + 1.0f);
            start[node] = gs + excl;
        }
        fh[tid] = excl;                       // -> cursors
    }
    __syncthreads();
    for (int i = tid; i < cnt; i += 1024) {
        unsigned r = grec[gs + i];
        int pos = atomicAdd(&fh[r & 511], 1);
        srcs[gs + pos] = (int)((r >> BSH) << 8);   // row * 256 = byte offset into hb
    }
}

// ---- transform-first: hb[row] = bf16( (x @ W^T)[row] * dis[row] ) via bf16 MFMA ----
__global__ __launch_bounds__(256) void k_hx(const float* __restrict__ x,
                                            const __bf16* __restrict__ wb,
                                            const float* __restrict__ dis,
                                            __bf16* __restrict__ hb) {
    int wave = threadIdx.x >> 6;
    int lane = threadIdx.x & 63;
    int strip = blockIdx.x * 4 + wave;
    if (strip >= N_STRIPS) return;
    int m0 = strip * 32;
    int l15 = lane & 15;
    int kq  = lane >> 4;

    bf16x8 a[2][4];
    #pragma unroll
    for (int mt = 0; mt < 2; ++mt) {
        const float* ap = x + (size_t)(m0 + mt * 16 + l15) * D + kq * 8;
        #pragma unroll
        for (int ks = 0; ks < 4; ++ks) {
            float4 lo = *(const float4*)(ap + ks * 32);
            float4 hi = *(const float4*)(ap + ks * 32 + 4);
            bf16x8 t;
            t[0] = (__bf16)lo.x; t[1] = (__bf16)lo.y;
            t[2] = (__bf16)lo.z; t[3] = (__bf16)lo.w;
            t[4] = (__bf16)hi.x; t[5] = (__bf16)hi.y;
            t[6] = (__bf16)hi.z; t[7] = (__bf16)hi.w;
            a[mt][ks] = t;
        }
    }

    f32x4 acc[2][8] = {};
    #pragma unroll
    for (int ks = 0; ks < 4; ++ks) {
        #pragma unroll
        for (int nt = 0; nt < 8; ++nt) {
            bf16x8 b = *(const bf16x8*)(wb + (size_t)(nt * 16 + l15) * D + ks * 32 + kq * 8);
            acc[0][nt] = __builtin_amdgcn_mfma_f32_16x16x32_bf16(a[0][ks], b, acc[0][nt], 0, 0, 0);
            acc[1][nt] = __builtin_amdgcn_mfma_f32_16x16x32_bf16(a[1][ks], b, acc[1][nt], 0, 0, 0);
        }
    }

    float dsv[2][4];
    #pragma unroll
    for (int mt = 0; mt < 2; ++mt)
        #pragma unroll
        for (int r = 0; r < 4; ++r)
            dsv[mt][r] = dis[m0 + mt * 16 + kq * 4 + r];

    #pragma unroll
    for (int nt = 0; nt < 8; ++nt) {
        int colj = nt * 16 + l15;
        #pragma unroll
        for (int mt = 0; mt < 2; ++mt) {
            #pragma unroll
            for (int r = 0; r < 4; ++r) {
                int rowi = m0 + mt * 16 + kq * 4 + r;
                hb[(size_t)rowi * D + colj] = (__bf16)(acc[mt][nt][r] * dsv[mt][r]);
            }
        }
    }
}

// ---- gather-aggregate: one wave per destination, 32 lanes x 8B per row,
// two source rows per VMEM instruction; srcs hold byte offsets already ----
__global__ __launch_bounds__(256) void k_aggregate(const int* __restrict__ srcs,
                                                   const int* __restrict__ start,
                                                   const int* __restrict__ deg,
                                                   const __bf16* __restrict__ hb,
                                                   const float* __restrict__ dis,
                                                   const float* __restrict__ bias,
                                                   float* __restrict__ out) {
    int node = (blockIdx.x * 256 + threadIdx.x) >> 6;
    int lane = threadIdx.x & 63;
    if (node >= N_NODES) return;
    int li   = lane & 31;          // 8B slot within row (cols 4*li .. 4*li+3)
    int half = lane >> 5;          // which of 2 edges this half-wave handles
    int s = start[node];
    int n = deg[node];
    float dc = dis[node];
    const unsigned char* hbase = (const unsigned char*)hb;
    size_t boff = (size_t)li * 8;

    float acc0 = 0.f, acc1 = 0.f, acc2 = 0.f, acc3 = 0.f;

    for (int base = 0; base < n; base += 64) {
        int m = n - base; if (m > 64) m = 64;
        int src_l = (lane < m) ? srcs[s + base + lane] : 0;   // byte offsets
        int i = 0;
        for (; i + 16 <= m; i += 16) {          // 16 edges per batch (8 per half)
            int sv[8]; uint2 av[8];
            #pragma unroll
            for (int j = 0; j < 8; ++j)
                sv[j] = __shfl(src_l, i + 2 * j + half);
            #pragma unroll
            for (int j = 0; j < 8; ++j)
                av[j] = *(const uint2*)(hbase + ((size_t)sv[j] + boff));
            #pragma unroll
            for (int j = 0; j < 8; ++j) {
                acc0 += __uint_as_float(av[j].x << 16);
                acc1 += __uint_as_float(av[j].x & 0xFFFF0000u);
                acc2 += __uint_as_float(av[j].y << 16);
                acc3 += __uint_as_float(av[j].y & 0xFFFF0000u);
            }
        }
        for (; i + 2 <= m; i += 2) {            // 2 edges per step
            int sj = __shfl(src_l, i + half);
            uint2 a = *(const uint2*)(hbase + ((size_t)sj + boff));
            acc0 += __uint_as_float(a.x << 16);
            acc1 += __uint_as_float(a.x & 0xFFFF0000u);
            acc2 += __uint_as_float(a.y << 16);
            acc3 += __uint_as_float(a.y & 0xFFFF0000u);
        }
        if (i < m) {                            // odd leftover: half 0 only
            int sj = __shfl(src_l, i);
            if (half == 0) {
                uint2 a = *(const uint2*)(hbase + ((size_t)sj + boff));
                acc0 += __uint_as_float(a.x << 16);
                acc1 += __uint_as_float(a.x & 0xFFFF0000u);
                acc2 += __uint_as_float(a.y << 16);
                acc3 += __uint_as_float(a.y & 0xFFFF0000u);
            }
        }
    }

    // combine the two halves
    acc0 += __shfl_xor(acc0, 32);
    acc1 += __shfl_xor(acc1, 32);
    acc2 += __shfl_xor(acc2, 32);
    acc3 += __shfl_xor(acc3, 32);

    if (half == 0) {
        // self-loop term (hb already prescaled by dis[node])
        uint2 a = *(const uint2*)(hbase + ((size_t)node * 256 + boff));
        acc0 += __uint_as_float(a.x << 16);
        acc1 += __uint_as_float(a.x & 0xFFFF0000u);
        acc2 += __uint_as_float(a.y << 16);
        acc3 += __uint_as_float(a.y & 0xFFFF0000u);

        float4 b4 = *(const float4*)(bias + li * 4);
        float4 r;
        r.x = fmaxf(acc0 * dc + b4.x, 0.f);
        r.y = fmaxf(acc1 * dc + b4.y, 0.f);
        r.z = fmaxf(acc2 * dc + b4.z, 0.f);
        r.w = fmaxf(acc3 * dc + b4.w, 0.f);
        *(float4*)(out + (size_t)node * D + li * 4) = r;
    }
}

extern "C" void kernel_launch(void* const* d_in, const int* in_sizes, int n_in,
                              void* d_out, int out_size, void* d_ws, size_t ws_size,
                              hipStream_t stream) {
    const float* x    = (const float*)d_in[0];
    const int*   ei   = (const int*)d_in[1];    // [2, E]: row then col
    const float* w    = (const float*)d_in[2];
    const float* bias = (const float*)d_in[3];
    float* out = (float*)d_out;

    char* ws = (char*)d_ws;
    int*      deg    = (int*)ws;              ws += N_NODES * 4;
    float*    dis    = (float*)ws;            ws += N_NODES * 4;
    int*      start  = (int*)ws;              ws += N_NODES * 4;
    int*      bhist  = (int*)ws;              ws += (size_t)NBKT * P_BLK * 4;
    int*      gtot   = (int*)ws;              ws += 512 * 4;
    int*      gstart = (int*)ws;              ws += 512 * 4;
    __bf16*   wb     = (__bf16*)ws;           ws += D * D * 2;
    unsigned* grec   = (unsigned*)ws;         ws += (size_t)N_EDGES * 4;
    int*      srcs   = (int*)ws;              ws += (size_t)N_EDGES * 4;
    __bf16*   hb     = (__bf16*)ws;           // N_NODES * D * 2 = 25.6 MB

    const int* row = ei;
    const int* col = ei + N_EDGES;

    k_prep     <<<P_BLK + 1, 1024, 0, stream>>>(col, (const float4*)w, bhist, (bf16x4*)wb);
    k_bscan    <<<NBKT, 512, 0, stream>>>(bhist, gtot);
    k_gscan    <<<1, 256, 0, stream>>>(gtot, gstart);
    k_cscatter <<<P_BLK, 1024, 0, stream>>>(row, col, bhist, gstart, grec);
    k_fine     <<<NBKT, 1024, 0, stream>>>(grec, gtot, gstart, deg, dis, start, srcs);
    k_hx       <<<(N_STRIPS + 3) / 4, 256, 0, stream>>>(x, wb, dis, hb);
    k_aggregate<<<(N_NODES * 64 + 255) / 256, 256, 0, stream>>>(srcs, start, deg, hb, dis, bias, out);
}

// Round 10
// 222.839 us; speedup vs baseline: 1.0586x; 1.0085x over previous
//
#include <hip/hip_runtime.h>

#define N_NODES 100000
#define N_EDGES 1600000
#define D 128
#define N_STRIPS (N_NODES / 32)     // 3125

#define BSH   9                     // coarse bucket = col >> 9 (512 nodes/bucket)
#define NBKT  196                   // ceil(100000 / 512)
#define P_BLK 512                   // partition blocks; EPB = 3125 exactly
#define EPB   (N_EDGES / P_BLK)

typedef __bf16 bf16x4 __attribute__((ext_vector_type(4)));
typedef __bf16 bf16x8 __attribute__((ext_vector_type(8)));
typedef float  f32x4  __attribute__((ext_vector_type(4)));

// ---- P1 fused: blocks 0..P_BLK-1 build coarse histogram; block P_BLK casts W ----
__global__ __launch_bounds__(1024) void k_prep(const int* __restrict__ col,
                                               const float4* __restrict__ w4,
                                               int* __restrict__ bhist,
                                               bf16x4* __restrict__ wb4) {
    int tid = threadIdx.x, b = blockIdx.x;
    if (b == P_BLK) {                      // cast W -> bf16 (4096 float4)
        for (int i = tid; i < (D * D) / 4; i += 1024) {
            float4 u = w4[i];
            bf16x4 p;
            p[0] = (__bf16)u.x; p[1] = (__bf16)u.y;
            p[2] = (__bf16)u.z; p[3] = (__bf16)u.w;
            wb4[i] = p;
        }
        return;
    }
    __shared__ int lh[NBKT];
    if (tid < NBKT) lh[tid] = 0;
    __syncthreads();
    int e0 = b * EPB;
    for (int e = e0 + tid; e < e0 + EPB; e += 1024)
        atomicAdd(&lh[col[e] >> BSH], 1);
    __syncthreads();
    if (tid < NBKT) bhist[tid * P_BLK + b] = lh[tid];
}

// ---- P2a: per-bucket exclusive scan over the 512 block counts (in place) ----
__global__ __launch_bounds__(512) void k_bscan(int* __restrict__ bhist,
                                               int* __restrict__ gtot) {
    __shared__ int buf[512];
    int k = blockIdx.x, t = threadIdx.x;
    int v = bhist[k * P_BLK + t];
    buf[t] = v;
    __syncthreads();
    for (int off = 1; off < 512; off <<= 1) {
        int u = (t >= off) ? buf[t - off] : 0;
        __syncthreads();
        buf[t] += u;
        __syncthreads();
    }
    bhist[k * P_BLK + t] = buf[t] - v;   // exclusive
    if (t == 511) gtot[k] = buf[511];
}

// ---- P2b: exclusive scan of bucket totals -> gstart ----
__global__ __launch_bounds__(256) void k_gscan(const int* __restrict__ gtot,
                                               int* __restrict__ gstart) {
    __shared__ int buf[256];
    int t = threadIdx.x;
    int v = (t < NBKT) ? gtot[t] : 0;
    buf[t] = v;
    __syncthreads();
    for (int off = 1; off < 256; off <<= 1) {
        int u = (t >= off) ? buf[t - off] : 0;
        __syncthreads();
        buf[t] += u;
        __syncthreads();
    }
    if (t < NBKT) gstart[t] = buf[t] - v;
}

// ---- P3: block-local counting sort in LDS, then COALESCED window writes:
// grec[i + doff[i]] = srt[i]; consecutive lanes write consecutive addresses
// within each bucket run ----
__global__ __launch_bounds__(1024) void k_cscatter(const int* __restrict__ row,
                                                   const int* __restrict__ col,
                                                   const int* __restrict__ bhist,
                                                   const int* __restrict__ gstart,
                                                   unsigned* __restrict__ grec) {
    __shared__ int      rec[EPB];          // packed (row<<9 | col&511)
    __shared__ unsigned short kb[EPB];     // bucket id per edge
    __shared__ int      srt[EPB];          // bucket-sorted records
    __shared__ int      dofp[EPB];         // per-record global offset delta
    __shared__ int      lh[256];           // local hist -> scan
    __shared__ int      sc[256];           // exclusive scan
    __shared__ int      cur[256];          // placement cursors
    __shared__ int      dofk[256];         // per-bucket dst delta
    int b = blockIdx.x, t = threadIdx.x;
    if (t < 256) lh[t] = 0;
    __syncthreads();
    int e0 = b * EPB;
    for (int i = t; i < EPB; i += 1024) {
        int r = row[e0 + i], c = col[e0 + i];
        int k = c >> BSH;
        rec[i] = (r << BSH) | (c & ((1 << BSH) - 1));
        kb[i]  = (unsigned short)k;
        atomicAdd(&lh[k], 1);
    }
    __syncthreads();
    int v = 0;
    if (t < 256) { v = lh[t]; sc[t] = v; }
    __syncthreads();
    for (int off = 1; off < 256; off <<= 1) {
        int u = 0;
        if (t < 256 && t >= off) u = sc[t - off];
        __syncthreads();
        if (t < 256) sc[t] += u;
        __syncthreads();
    }
    if (t < 256) {
        int excl = sc[t] - v;              // local exclusive base
        sc[t]  = excl;
        cur[t] = 0;
        dofk[t] = (t < NBKT) ? (gstart[t] + bhist[t * P_BLK + b] - excl) : 0;
    }
    __syncthreads();
    for (int i = t; i < EPB; i += 1024) {
        int k = kb[i];
        int p = sc[k] + atomicAdd(&cur[k], 1);
        srt[p]  = rec[i];
        dofp[p] = dofk[k];
    }
    __syncthreads();
    for (int i = t; i < EPB; i += 1024)
        grec[i + dofp[i]] = (unsigned)srt[i];
}

// ---- P4: per-bucket fine sort (512 nodes/bucket); emits deg/dis/start and
// srcs as pre-shifted byte offsets into hb ----
__global__ __launch_bounds__(1024) void k_fine(const unsigned* __restrict__ grec,
                                               const int* __restrict__ gtot,
                                               const int* __restrict__ gstart,
                                               int* __restrict__ deg,
                                               float* __restrict__ dis,
                                               int* __restrict__ start,
                                               int* __restrict__ srcs) {
    __shared__ int fh[512];
    __shared__ int fsc[512];
    int b = blockIdx.x;
    int tid = threadIdx.x;
    int cnt = gtot[b];
    int gs = gstart[b];
    if (tid < 512) fh[tid] = 0;
    __syncthreads();
    for (int i = tid; i < cnt; i += 1024)
        atomicAdd(&fh[grec[gs + i] & 511], 1);
    __syncthreads();
    int v = 0;
    if (tid < 512) { v = fh[tid]; fsc[tid] = v; }
    __syncthreads();
    for (int off = 1; off < 512; off <<= 1) {
        int u = 0;
        if (tid < 512 && tid >= off) u = fsc[tid - off];
        __syncthreads();
        if (tid < 512) fsc[tid] += u;
        __syncthreads();
    }
    if (tid < 512) {
        int excl = fsc[tid] - v;              // exclusive scan value
        int node = (b << BSH) + tid;
        if (node < N_NODES) {
            deg[node]   = v;
            dis[node]   = rsqrtf((float)v + 1.0f);
            start[node] = gs + excl;
        }
        fh[tid] = excl;                       // -> cursors
    }
    __syncthreads();
    for (int i = tid; i < cnt; i += 1024) {
        unsigned r = grec[gs + i];
        int pos = atomicAdd(&fh[r & 511], 1);
        srcs[gs + pos] = (int)((r >> BSH) << 8);   // row * 256 = byte offset into hb
    }
}

// ---- transform-first: hb[row] = bf16( (x @ W^T)[row] * dis[row] ) via bf16 MFMA ----
__global__ __launch_bounds__(256) void k_hx(const float* __restrict__ x,
                                            const __bf16* __restrict__ wb,
                                            const float* __restrict__ dis,
                                            __bf16* __restrict__ hb) {
    int wave = threadIdx.x >> 6;
    int lane = threadIdx.x & 63;
    int strip = blockIdx.x * 4 + wave;
    if (strip >= N_STRIPS) return;
    int m0 = strip * 32;
    int l15 = lane & 15;
    int kq  = lane >> 4;

    bf16x8 a[2][4];
    #pragma unroll
    for (int mt = 0; mt < 2; ++mt) {
        const float* ap = x + (size_t)(m0 + mt * 16 + l15) * D + kq * 8;
        #pragma unroll
        for (int ks = 0; ks < 4; ++ks) {
            float4 lo = *(const float4*)(ap + ks * 32);
            float4 hi = *(const float4*)(ap + ks * 32 + 4);
            bf16x8 t;
            t[0] = (__bf16)lo.x; t[1] = (__bf16)lo.y;
            t[2] = (__bf16)lo.z; t[3] = (__bf16)lo.w;
            t[4] = (__bf16)hi.x; t[5] = (__bf16)hi.y;
            t[6] = (__bf16)hi.z; t[7] = (__bf16)hi.w;
            a[mt][ks] = t;
        }
    }

    f32x4 acc[2][8] = {};
    #pragma unroll
    for (int ks = 0; ks < 4; ++ks) {
        #pragma unroll
        for (int nt = 0; nt < 8; ++nt) {
            bf16x8 b = *(const bf16x8*)(wb + (size_t)(nt * 16 + l15) * D + ks * 32 + kq * 8);
            acc[0][nt] = __builtin_amdgcn_mfma_f32_16x16x32_bf16(a[0][ks], b, acc[0][nt], 0, 0, 0);
            acc[1][nt] = __builtin_amdgcn_mfma_f32_16x16x32_bf16(a[1][ks], b, acc[1][nt], 0, 0, 0);
        }
    }

    float dsv[2][4];
    #pragma unroll
    for (int mt = 0; mt < 2; ++mt)
        #pragma unroll
        for (int r = 0; r < 4; ++r)
            dsv[mt][r] = dis[m0 + mt * 16 + kq * 4 + r];

    #pragma unroll
    for (int nt = 0; nt < 8; ++nt) {
        int colj = nt * 16 + l15;
        #pragma unroll
        for (int mt = 0; mt < 2; ++mt) {
            #pragma unroll
            for (int r = 0; r < 4; ++r) {
                int rowi = m0 + mt * 16 + kq * 4 + r;
                hb[(size_t)rowi * D + colj] = (__bf16)(acc[mt][nt][r] * dsv[mt][r]);
            }
        }
    }
}

// ---- gather-aggregate: one wave per destination; FOUR source rows per VMEM
// instruction (4 quarter-groups x 16 lanes x dwordx4 = 16B/lane); shuffles
// halved (1 per 4 edges); cross-quarter combine via shfl_xor(16/32) ----
__global__ __launch_bounds__(256) void k_aggregate(const int* __restrict__ srcs,
                                                   const int* __restrict__ start,
                                                   const int* __restrict__ deg,
                                                   const __bf16* __restrict__ hb,
                                                   const float* __restrict__ dis,
                                                   const float* __restrict__ bias,
                                                   float* __restrict__ out) {
    int node = (blockIdx.x * 256 + threadIdx.x) >> 6;
    int lane = threadIdx.x & 63;
    if (node >= N_NODES) return;
    int li = lane & 15;            // 16B slot within row (cols 8*li .. 8*li+7)
    int q  = lane >> 4;            // quarter: which of 4 edges per instruction
    int s = start[node];
    int n = deg[node];
    float dc = dis[node];
    const unsigned char* hbase = (const unsigned char*)hb;
    size_t boff = (size_t)li * 16;

    float a0 = 0.f, a1 = 0.f, a2 = 0.f, a3 = 0.f;
    float a4 = 0.f, a5 = 0.f, a6 = 0.f, a7 = 0.f;

#define ACC8(v)                                          \
    do {                                                 \
        a0 += __uint_as_float((v).x << 16);              \
        a1 += __uint_as_float((v).x & 0xFFFF0000u);      \
        a2 += __uint_as_float((v).y << 16);              \
        a3 += __uint_as_float((v).y & 0xFFFF0000u);      \
        a4 += __uint_as_float((v).z << 16);              \
        a5 += __uint_as_float((v).z & 0xFFFF0000u);      \
        a6 += __uint_as_float((v).w << 16);              \
        a7 += __uint_as_float((v).w & 0xFFFF0000u);      \
    } while (0)

    for (int base = 0; base < n; base += 64) {
        int m = n - base; if (m > 64) m = 64;
        int src_l = (lane < m) ? srcs[s + base + lane] : 0;   // byte offsets
        int i = 0;
        for (; i + 16 <= m; i += 16) {          // 16 edges per batch (4 per instr)
            int sv[4]; uint4 av[4];
            #pragma unroll
            for (int j = 0; j < 4; ++j)
                sv[j] = __shfl(src_l, i + 4 * j + q);
            #pragma unroll
            for (int j = 0; j < 4; ++j)
                av[j] = *(const uint4*)(hbase + ((size_t)sv[j] + boff));
            #pragma unroll
            for (int j = 0; j < 4; ++j)
                ACC8(av[j]);
        }
        for (; i + 4 <= m; i += 4) {            // 4 edges per step
            int sj = __shfl(src_l, i + q);
            uint4 a = *(const uint4*)(hbase + ((size_t)sj + boff));
            ACC8(a);
        }
        if (i < m) {                            // tail: r in {1,2,3} edges
            int sj = __shfl(src_l, i + q);
            if (q < m - i) {
                uint4 a = *(const uint4*)(hbase + ((size_t)sj + boff));
                ACC8(a);
            }
        }
    }

    // combine the four quarters
    a0 += __shfl_xor(a0, 16); a0 += __shfl_xor(a0, 32);
    a1 += __shfl_xor(a1, 16); a1 += __shfl_xor(a1, 32);
    a2 += __shfl_xor(a2, 16); a2 += __shfl_xor(a2, 32);
    a3 += __shfl_xor(a3, 16); a3 += __shfl_xor(a3, 32);
    a4 += __shfl_xor(a4, 16); a4 += __shfl_xor(a4, 32);
    a5 += __shfl_xor(a5, 16); a5 += __shfl_xor(a5, 32);
    a6 += __shfl_xor(a6, 16); a6 += __shfl_xor(a6, 32);
    a7 += __shfl_xor(a7, 16); a7 += __shfl_xor(a7, 32);

    if (q == 0) {
        // self-loop term (hb already prescaled by dis[node])
        uint4 a = *(const uint4*)(hbase + ((size_t)node * 256 + boff));
        ACC8(a);

        float4 b0 = *(const float4*)(bias + li * 8);
        float4 b1 = *(const float4*)(bias + li * 8 + 4);
        float4 r0, r1;
        r0.x = fmaxf(a0 * dc + b0.x, 0.f);
        r0.y = fmaxf(a1 * dc + b0.y, 0.f);
        r0.z = fmaxf(a2 * dc + b0.z, 0.f);
        r0.w = fmaxf(a3 * dc + b0.w, 0.f);
        r1.x = fmaxf(a4 * dc + b1.x, 0.f);
        r1.y = fmaxf(a5 * dc + b1.y, 0.f);
        r1.z = fmaxf(a6 * dc + b1.z, 0.f);
        r1.w = fmaxf(a7 * dc + b1.w, 0.f);
        *(float4*)(out + (size_t)node * D + li * 8)     = r0;
        *(float4*)(out + (size_t)node * D + li * 8 + 4) = r1;
    }
#undef ACC8
}

extern "C" void kernel_launch(void* const* d_in, const int* in_sizes, int n_in,
                              void* d_out, int out_size, void* d_ws, size_t ws_size,
                              hipStream_t stream) {
    const float* x    = (const float*)d_in[0];
    const int*   ei   = (const int*)d_in[1];    // [2, E]: row then col
    const float* w    = (const float*)d_in[2];
    const float* bias = (const float*)d_in[3];
    float* out = (float*)d_out;

    char* ws = (char*)d_ws;
    int*      deg    = (int*)ws;              ws += N_NODES * 4;
    float*    dis    = (float*)ws;            ws += N_NODES * 4;
    int*      start  = (int*)ws;              ws += N_NODES * 4;
    int*      bhist  = (int*)ws;              ws += (size_t)NBKT * P_BLK * 4;
    int*      gtot   = (int*)ws;              ws += 512 * 4;
    int*      gstart = (int*)ws;              ws += 512 * 4;
    __bf16*   wb     = (__bf16*)ws;           ws += D * D * 2;
    unsigned* grec   = (unsigned*)ws;         ws += (size_t)N_EDGES * 4;
    int*      srcs   = (int*)ws;              ws += (size_t)N_EDGES * 4;
    __bf16*   hb     = (__bf16*)ws;           // N_NODES * D * 2 = 25.6 MB

    const int* row = ei;
    const int* col = ei + N_EDGES;

    k_prep     <<<P_BLK + 1, 1024, 0, stream>>>(col, (const float4*)w, bhist, (bf16x4*)wb);
    k_bscan    <<<NBKT, 512, 0, stream>>>(bhist, gtot);
    k_gscan    <<<1, 256, 0, stream>>>(gtot, gstart);
    k_cscatter <<<P_BLK, 1024, 0, stream>>>(row, col, bhist, gstart, grec);
    k_fine     <<<NBKT, 1024, 0, stream>>>(grec, gtot, gstart, deg, dis, start, srcs);
    k_hx       <<<(N_STRIPS + 3) / 4, 256, 0, stream>>>(x, wb, dis, hb);
    k_aggregate<<<(N_NODES * 64 + 255) / 256, 256, 0, stream>>>(srcs, start, deg, hb, dis, bias, out);
}